// Round 2
// baseline (1549.074 us; speedup 1.0000x reference)
//
#include <hip/hip_runtime.h>

#define D 128
#define NLAYERS 3
#define BN_EPS 1e-5f

// ---------------- setup kernels ----------------

__global__ void k_hist_edges(const int* __restrict__ dst, int* __restrict__ cnt, int E) {
    int i = blockIdx.x * blockDim.x + threadIdx.x;
    if (i < E) atomicAdd(&cnt[dst[i]], 1);
}

__global__ void k_hist_batch(const int* __restrict__ batch, int* __restrict__ gcnt, int N) {
    int i = blockIdx.x * blockDim.x + threadIdx.x;
    if (i < N) atomicAdd(&gcnt[batch[i]], 1);
}

__global__ void k_dinv(const int* __restrict__ cnt, float* __restrict__ dinv, int N) {
    int i = blockIdx.x * blockDim.x + threadIdx.x;
    if (i < N) dinv[i] = rsqrtf((float)(cnt[i] + 1));   // +1 self loop
}

// partial sums of blocks of 1024 counts
__global__ void k_scan_partial(const int* __restrict__ cnt, int* __restrict__ bsum, int N) {
    __shared__ int sh[256];
    int b = blockIdx.x, t = threadIdx.x;
    int base = b * 1024 + t * 4;
    int s = 0;
#pragma unroll
    for (int i = 0; i < 4; ++i) { int idx = base + i; s += (idx < N) ? cnt[idx] : 0; }
    sh[t] = s;
    for (int ofs = 128; ofs > 0; ofs >>= 1) {
        __syncthreads();
        if (t < ofs) sh[t] += sh[t + ofs];
    }
    __syncthreads();
    if (t == 0) bsum[b] = sh[0];
}

// exclusive scan of up to 256 block sums (single block, 256 threads)
__global__ void k_scan_small(const int* __restrict__ bsum, int* __restrict__ bbase, int nb) {
    __shared__ int sh[256];
    int t = threadIdx.x;
    int v = (t < nb) ? bsum[t] : 0;
    sh[t] = v;
    __syncthreads();
    for (int ofs = 1; ofs < 256; ofs <<= 1) {
        int vv = (t >= ofs) ? sh[t - ofs] : 0;
        __syncthreads();
        sh[t] += vv;
        __syncthreads();
    }
    bbase[t] = sh[t] - v;   // exclusive
}

__global__ void k_scan_apply(const int* __restrict__ cnt, const int* __restrict__ bbase,
                             int* __restrict__ roff, int* __restrict__ cur, int N) {
    __shared__ int sh[256];
    int b = blockIdx.x, t = threadIdx.x;
    int base = b * 1024 + t * 4;
    int v[4]; int s = 0;
#pragma unroll
    for (int i = 0; i < 4; ++i) { v[i] = (base + i < N) ? cnt[base + i] : 0; s += v[i]; }
    sh[t] = s;
    __syncthreads();
    for (int ofs = 1; ofs < 256; ofs <<= 1) {
        int vv = (t >= ofs) ? sh[t - ofs] : 0;
        __syncthreads();
        sh[t] += vv;
        __syncthreads();
    }
    int o = bbase[b] + sh[t] - s;
#pragma unroll
    for (int i = 0; i < 4; ++i) {
        int idx = base + i;
        if (idx < N) {
            roff[idx] = o; cur[idx] = o;
            o += v[i];
            if (idx == N - 1) roff[N] = o;
        }
    }
}

// scan of graph counts (G <= 1024), single block of 256 threads
__global__ void k_gscan(const int* __restrict__ gcnt, int* __restrict__ goff, int G, int N) {
    __shared__ int sh[256];
    int t = threadIdx.x;
    int base = t * 4;
    int v[4]; int s = 0;
#pragma unroll
    for (int i = 0; i < 4; ++i) { v[i] = (base + i < G) ? gcnt[base + i] : 0; s += v[i]; }
    sh[t] = s;
    __syncthreads();
    for (int ofs = 1; ofs < 256; ofs <<= 1) {
        int vv = (t >= ofs) ? sh[t - ofs] : 0;
        __syncthreads();
        sh[t] += vv;
        __syncthreads();
    }
    int o = sh[t] - s;
#pragma unroll
    for (int i = 0; i < 4; ++i) {
        int idx = base + i;
        if (idx < G) { goff[idx] = o; o += v[i]; }
    }
    if (t == 255) goff[G] = N;
}

__global__ void k_fill(const int* __restrict__ src, const int* __restrict__ dst,
                       int* __restrict__ cur, int* __restrict__ csr, int E) {
    int i = blockIdx.x * blockDim.x + threadIdx.x;
    if (i < E) {
        int p = atomicAdd(&cur[dst[i]], 1);
        csr[p] = src[i];
    }
}

__global__ void k_init_ac(float* __restrict__ a, float* __restrict__ c) {
    int t = threadIdx.x;
    a[t] = 1.0f; c[t] = 0.0f;
}

// Wf[k][j] = a[k]*W[k][j], same for rW
__global__ void k_fold_scale(const float* __restrict__ W, const float* __restrict__ rW,
                             const float* __restrict__ a,
                             float* __restrict__ Wf, float* __restrict__ rWf) {
    int idx = blockIdx.x * 256 + threadIdx.x;  // grid 128 -> 32768 threads
    if (idx < D * D) {
        int k = idx >> 7;
        Wf[idx] = a[k] * W[idx];
    } else {
        int li = idx - D * D;
        int k = li >> 7;
        rWf[li] = a[k] * rW[li];
    }
}

// cwA[j] = sum_k c[k]*W[k][j];  crb[j] = rb[j] + sum_k c[k]*rW[k][j]
__global__ void k_fold_vec(const float* __restrict__ W, const float* __restrict__ rW,
                           const float* __restrict__ c, const float* __restrict__ rb,
                           float* __restrict__ cwA, float* __restrict__ crb) {
    int t = threadIdx.x;  // 256
    if (t < D) {
        float s = 0.f;
        for (int k = 0; k < D; ++k) s += c[k] * W[k * D + t];
        cwA[t] = s;
    } else {
        int j = t - D;
        float s = rb[j];
        for (int k = 0; k < D; ++k) s += c[k] * rW[k * D + j];
        crb[j] = s;
    }
}

// ---------------- fused dual GEMM ----------------
// O0 = F @ W0 + add0 ;  O1 = relu(F @ W1 + add1)
__global__ __launch_bounds__(256) void k_gemm_dual(
    const float* __restrict__ F,
    const float* __restrict__ W0, const float* __restrict__ W1,
    const float* __restrict__ add0, const float* __restrict__ add1,
    float* __restrict__ O0, float* __restrict__ O1, int N) {
    __shared__ float fs[128 * 128];
    const int t = threadIdx.x;
    const int rowbase = blockIdx.x * 128;

    // stage 128x128 f tile, XOR-swizzled on 16B units: su = unit ^ ((row>>3)&7)
#pragma unroll
    for (int i = 0; i < 16; ++i) {
        int l = t + i * 256;          // float4 index 0..4095
        int row = l >> 5;
        int unit = l & 31;
        float4 v = make_float4(0.f, 0.f, 0.f, 0.f);
        int gr = rowbase + row;
        if (gr < N) v = *(const float4*)(F + (size_t)gr * D + unit * 4);
        int su = unit ^ ((row >> 3) & 7);
        *(float4*)&fs[row * 128 + su * 4] = v;
    }
    __syncthreads();

    const int tx = t & 15, ty = t >> 4;
    const int c0 = tx * 8;
    const int r0 = ty * 8;

#pragma unroll 1
    for (int m = 0; m < 2; ++m) {
        const float* __restrict__ W = m ? W1 : W0;
        const float* __restrict__ addv = m ? add1 : add0;
        float* __restrict__ O = m ? O1 : O0;

        float acc[8][8];
#pragma unroll
        for (int i = 0; i < 8; ++i)
#pragma unroll
            for (int j = 0; j < 8; ++j) acc[i][j] = 0.f;

        for (int kc = 0; kc < 128; kc += 4) {
            float fr[8][4];
#pragma unroll
            for (int i = 0; i < 8; ++i) {
                int rr = r0 + i;
                int su = (kc >> 2) ^ ((rr >> 3) & 7);
                float4 t4 = *(const float4*)&fs[rr * 128 + su * 4];
                fr[i][0] = t4.x; fr[i][1] = t4.y; fr[i][2] = t4.z; fr[i][3] = t4.w;
            }
#pragma unroll
            for (int kk = 0; kk < 4; ++kk) {
                float4 wa = *(const float4*)(W + (size_t)(kc + kk) * D + c0);
                float4 wb = *(const float4*)(W + (size_t)(kc + kk) * D + c0 + 4);
                float wv[8] = {wa.x, wa.y, wa.z, wa.w, wb.x, wb.y, wb.z, wb.w};
#pragma unroll
                for (int i = 0; i < 8; ++i) {
                    float fv = fr[i][kk];
#pragma unroll
                    for (int j = 0; j < 8; ++j) acc[i][j] += fv * wv[j];
                }
            }
        }

        float va[8];
#pragma unroll
        for (int j = 0; j < 8; ++j) va[j] = addv[c0 + j];

#pragma unroll
        for (int i = 0; i < 8; ++i) {
            int gr = rowbase + r0 + i;
            if (gr < N) {
                float o0 = acc[i][0] + va[0], o1 = acc[i][1] + va[1];
                float o2 = acc[i][2] + va[2], o3 = acc[i][3] + va[3];
                float o4 = acc[i][4] + va[4], o5 = acc[i][5] + va[5];
                float o6 = acc[i][6] + va[6], o7 = acc[i][7] + va[7];
                if (m == 1) {
                    o0 = fmaxf(o0, 0.f); o1 = fmaxf(o1, 0.f); o2 = fmaxf(o2, 0.f); o3 = fmaxf(o3, 0.f);
                    o4 = fmaxf(o4, 0.f); o5 = fmaxf(o5, 0.f); o6 = fmaxf(o6, 0.f); o7 = fmaxf(o7, 0.f);
                }
                float4 lo = make_float4(o0, o1, o2, o3);
                float4 hi = make_float4(o4, o5, o6, o7);
                *(float4*)(O + (size_t)gr * D + c0) = lo;
                *(float4*)(O + (size_t)gr * D + c0 + 4) = hi;
            }
        }
    }
}

// ---------------- aggregation + residual + BN stats ----------------
// 2 nodes per wave (32 lanes x float4 each), 4-wide edge unroll for MLP.
// resf is read for own row then overwritten with the layer output (in-place).
__global__ __launch_bounds__(256) void k_agg(
    const float* __restrict__ h, float* __restrict__ resf,
    const int* __restrict__ roff, const int* __restrict__ csr,
    const float* __restrict__ dinv, const float* __restrict__ bias,
    float* __restrict__ stats, int N) {
    const int tid = threadIdx.x;
    const int lane = tid & 63;
    const int half = lane >> 5;          // which node of the pair
    const int c = (lane & 31) * 4;       // column group
    const int wid = (blockIdx.x * blockDim.x + tid) >> 6;
    const int nw = (gridDim.x * blockDim.x) >> 6;
    const float4 bv = *(const float4*)(bias + c);

    float sx = 0.f, sy = 0.f, sz = 0.f, sw = 0.f;
    float qx = 0.f, qy = 0.f, qz = 0.f, qw = 0.f;

    const int NP = (N + 1) >> 1;
    for (int p = wid; p < NP; p += nw) {
        int v = p * 2 + half;
        if (v < N) {
            int e = roff[v], end = roff[v + 1];
            float ax = 0.f, ay = 0.f, az = 0.f, aw = 0.f;
            for (; e + 4 <= end; e += 4) {
                int u0 = csr[e], u1 = csr[e + 1], u2 = csr[e + 2], u3 = csr[e + 3];
                float w0 = dinv[u0], w1 = dinv[u1], w2 = dinv[u2], w3 = dinv[u3];
                const float4 h0 = *(const float4*)(h + (size_t)u0 * D + c);
                const float4 h1 = *(const float4*)(h + (size_t)u1 * D + c);
                const float4 h2 = *(const float4*)(h + (size_t)u2 * D + c);
                const float4 h3 = *(const float4*)(h + (size_t)u3 * D + c);
                ax += w0 * h0.x + w1 * h1.x + w2 * h2.x + w3 * h3.x;
                ay += w0 * h0.y + w1 * h1.y + w2 * h2.y + w3 * h3.y;
                az += w0 * h0.z + w1 * h1.z + w2 * h2.z + w3 * h3.z;
                aw += w0 * h0.w + w1 * h1.w + w2 * h2.w + w3 * h3.w;
            }
            for (; e < end; ++e) {
                int u = csr[e];
                float w = dinv[u];
                const float4 hv = *(const float4*)(h + (size_t)u * D + c);
                ax += w * hv.x; ay += w * hv.y; az += w * hv.z; aw += w * hv.w;
            }
            float dv = dinv[v];
            float dv2 = dv * dv;
            const float4 hs = *(const float4*)(h + (size_t)v * D + c);
            ax = ax * dv + hs.x * dv2 + bv.x;
            ay = ay * dv + hs.y * dv2 + bv.y;
            az = az * dv + hs.z * dv2 + bv.z;
            aw = aw * dv + hs.w * dv2 + bv.w;
            // NOTE: edge weights need dinv[v]*dinv[u]; we folded dinv[v] by scaling the
            // edge sum once at the end (ax*dv), self-loop uses dv*dv.
            const float4 r = *(const float4*)(resf + (size_t)v * D + c);
            float ox = ax + r.x, oy = ay + r.y, oz = az + r.z, ow = aw + r.w;
            *(float4*)(resf + (size_t)v * D + c) = make_float4(ox, oy, oz, ow);
            sx += ox; sy += oy; sz += oz; sw += ow;
            qx += ox * ox; qy += oy * oy; qz += oz * oz; qw += ow * ow;
        }
    }

    __shared__ float4 rs[256];
    __shared__ float4 rq[256];
    rs[tid] = make_float4(sx, sy, sz, sw);
    rq[tid] = make_float4(qx, qy, qz, qw);
    __syncthreads();
    if (tid < 32) {
        float4 s = rs[tid], q = rq[tid];
#pragma unroll
        for (int k = 1; k < 8; ++k) {
            float4 s2 = rs[tid + 32 * k], q2 = rq[tid + 32 * k];
            s.x += s2.x; s.y += s2.y; s.z += s2.z; s.w += s2.w;
            q.x += q2.x; q.y += q2.y; q.z += q2.z; q.w += q2.w;
        }
        int cc = tid * 4;   // == column group for tid<32
        atomicAdd(&stats[cc + 0], s.x);
        atomicAdd(&stats[cc + 1], s.y);
        atomicAdd(&stats[cc + 2], s.z);
        atomicAdd(&stats[cc + 3], s.w);
        atomicAdd(&stats[D + cc + 0], q.x);
        atomicAdd(&stats[D + cc + 1], q.y);
        atomicAdd(&stats[D + cc + 2], q.z);
        atomicAdd(&stats[D + cc + 3], q.w);
    }
}

__global__ void k_bnfin(const float* __restrict__ stats, const float* __restrict__ gamma,
                        const float* __restrict__ beta,
                        float* __restrict__ a_next, float* __restrict__ c_next, float invN) {
    int t = threadIdx.x;  // 128
    float mean = stats[t] * invN;
    float var = stats[D + t] * invN - mean * mean;
    float rs = rsqrtf(var + BN_EPS);
    float a = gamma[t] * rs;
    a_next[t] = a;
    c_next[t] = beta[t] - mean * a;
}

// out[g] = (sum_{v in g} f[v]) * a + cnt_g * c
__global__ void k_pool(const float* __restrict__ f, const int* __restrict__ goff,
                       const float* __restrict__ a, const float* __restrict__ c,
                       float* __restrict__ out) {
    int g = blockIdx.x, t = threadIdx.x;  // 128 threads
    int beg = goff[g], end = goff[g + 1];
    float acc = 0.f;
    for (int v = beg; v < end; ++v) acc += f[(size_t)v * D + t];
    out[(size_t)g * D + t] = acc * a[t] + (float)(end - beg) * c[t];
}

// ---------------- launcher ----------------

extern "C" void kernel_launch(void* const* d_in, const int* in_sizes, int n_in,
                              void* d_out, int out_size, void* d_ws, size_t ws_size,
                              hipStream_t stream) {
    const float* x      = (const float*)d_in[0];
    const int*   ei     = (const int*)d_in[1];
    const int*   batch  = (const int*)d_in[2];
    const float* Ws     = (const float*)d_in[3];
    const float* bs     = (const float*)d_in[4];
    const float* rWs    = (const float*)d_in[5];
    const float* rbs    = (const float*)d_in[6];
    const float* gammas = (const float*)d_in[7];
    const float* betas  = (const float*)d_in[8];
    float* out = (float*)d_out;

    const int N = in_sizes[2];
    const int E = in_sizes[1] / 2;
    const int G = out_size / D;
    const int* src = ei;
    const int* dst = ei + E;

    char* ws = (char*)d_ws;
    size_t off = 0;
    auto alloc = [&](size_t bytes) -> char* {
        char* p = ws + off;
        off += (bytes + 255) & ~(size_t)255;
        return p;
    };
    float* h    = (float*)alloc((size_t)N * D * 4);
    float* R0   = (float*)alloc((size_t)N * D * 4);
    float* R1   = (float*)alloc((size_t)N * D * 4);
    int*   csr  = (int*)alloc((size_t)E * 4);
    int*   roff = (int*)alloc((size_t)(N + 1) * 4);
    int*   cur  = (int*)alloc((size_t)N * 4);
    int*   cnt  = (int*)alloc((size_t)N * 4);
    float* dinv = (float*)alloc((size_t)N * 4);
    int*   gcnt = (int*)alloc((size_t)G * 4);
    int*   goff = (int*)alloc((size_t)(G + 1) * 4);
    int*   bsum = (int*)alloc(256 * 4);
    int*   bbase= (int*)alloc(256 * 4);
    float* stats= (float*)alloc((size_t)NLAYERS * 2 * D * 4);
    float* aarr = (float*)alloc((size_t)(NLAYERS + 1) * D * 4);
    float* carr = (float*)alloc((size_t)(NLAYERS + 1) * D * 4);
    float* Wf   = (float*)alloc((size_t)D * D * 4);
    float* rWf  = (float*)alloc((size_t)D * D * 4);
    float* cwA  = (float*)alloc(D * 4);
    float* crb  = (float*)alloc(D * 4);
    (void)ws_size;

    hipMemsetAsync(cnt, 0, (size_t)N * 4, stream);
    hipMemsetAsync(gcnt, 0, (size_t)G * 4, stream);
    hipMemsetAsync(stats, 0, (size_t)NLAYERS * 2 * D * 4, stream);

    k_hist_edges<<<(E + 255) / 256, 256, 0, stream>>>(dst, cnt, E);
    k_hist_batch<<<(N + 255) / 256, 256, 0, stream>>>(batch, gcnt, N);
    k_dinv<<<(N + 255) / 256, 256, 0, stream>>>(cnt, dinv, N);

    int nb = (N + 1023) / 1024;
    k_scan_partial<<<nb, 256, 0, stream>>>(cnt, bsum, N);
    k_scan_small<<<1, 256, 0, stream>>>(bsum, bbase, nb);
    k_scan_apply<<<nb, 256, 0, stream>>>(cnt, bbase, roff, cur, N);
    k_gscan<<<1, 256, 0, stream>>>(gcnt, goff, G, N);
    k_fill<<<(E + 255) / 256, 256, 0, stream>>>(src, dst, cur, csr, E);
    k_init_ac<<<1, D, 0, stream>>>(aarr, carr);

    const float* fin = x;
    float* fouts[NLAYERS] = {R0, R1, R0};
    for (int l = 0; l < NLAYERS; ++l) {
        const float* W  = Ws + (size_t)l * D * D;
        const float* rW = rWs + (size_t)l * D * D;
        const float* aP = aarr + (size_t)l * D;
        const float* cP = carr + (size_t)l * D;

        k_fold_scale<<<128, 256, 0, stream>>>(W, rW, aP, Wf, rWf);
        k_fold_vec<<<1, 256, 0, stream>>>(W, rW, cP, rbs + (size_t)l * D, cwA, crb);

        float* fo = fouts[l];
        k_gemm_dual<<<(N + 127) / 128, 256, 0, stream>>>(fin, Wf, rWf, cwA, crb, h, fo, N);
        k_agg<<<2048, 256, 0, stream>>>(h, fo, roff, csr, dinv, bs + (size_t)l * D,
                                        stats + (size_t)l * 2 * D, N);
        k_bnfin<<<1, D, 0, stream>>>(stats + (size_t)l * 2 * D, gammas + (size_t)l * D,
                                     betas + (size_t)l * D,
                                     aarr + (size_t)(l + 1) * D, carr + (size_t)(l + 1) * D,
                                     1.0f / (float)N);
        fin = fo;
    }

    k_pool<<<G, D, 0, stream>>>(fin, goff, aarr + (size_t)NLAYERS * D,
                                carr + (size_t)NLAYERS * D, out);
}

// Round 3
// 1476.515 us; speedup vs baseline: 1.0491x; 1.0491x over previous
//
#include <hip/hip_runtime.h>

#define D 128
#define NLAYERS 3
#define BN_EPS 1e-5f

// ---------------- setup kernels ----------------

__global__ void k_hist_edges(const int* __restrict__ dst, int* __restrict__ cnt, int E) {
    int i = blockIdx.x * blockDim.x + threadIdx.x;
    if (i < E) atomicAdd(&cnt[dst[i]], 1);
}

__global__ void k_hist_batch(const int* __restrict__ batch, int* __restrict__ gcnt, int N) {
    int i = blockIdx.x * blockDim.x + threadIdx.x;
    if (i < N) atomicAdd(&gcnt[batch[i]], 1);
}

__global__ void k_dinv(const int* __restrict__ cnt, float* __restrict__ dinv, int N) {
    int i = blockIdx.x * blockDim.x + threadIdx.x;
    if (i < N) dinv[i] = rsqrtf((float)(cnt[i] + 1));   // +1 self loop
}

// partial sums of blocks of 1024 counts
__global__ void k_scan_partial(const int* __restrict__ cnt, int* __restrict__ bsum, int N) {
    __shared__ int sh[256];
    int b = blockIdx.x, t = threadIdx.x;
    int base = b * 1024 + t * 4;
    int s = 0;
#pragma unroll
    for (int i = 0; i < 4; ++i) { int idx = base + i; s += (idx < N) ? cnt[idx] : 0; }
    sh[t] = s;
    for (int ofs = 128; ofs > 0; ofs >>= 1) {
        __syncthreads();
        if (t < ofs) sh[t] += sh[t + ofs];
    }
    __syncthreads();
    if (t == 0) bsum[b] = sh[0];
}

// exclusive scan of up to 256 block sums (single block, 256 threads)
__global__ void k_scan_small(const int* __restrict__ bsum, int* __restrict__ bbase, int nb) {
    __shared__ int sh[256];
    int t = threadIdx.x;
    int v = (t < nb) ? bsum[t] : 0;
    sh[t] = v;
    __syncthreads();
    for (int ofs = 1; ofs < 256; ofs <<= 1) {
        int vv = (t >= ofs) ? sh[t - ofs] : 0;
        __syncthreads();
        sh[t] += vv;
        __syncthreads();
    }
    bbase[t] = sh[t] - v;   // exclusive
}

__global__ void k_scan_apply(const int* __restrict__ cnt, const int* __restrict__ bbase,
                             int* __restrict__ roff, int* __restrict__ cur, int N) {
    __shared__ int sh[256];
    int b = blockIdx.x, t = threadIdx.x;
    int base = b * 1024 + t * 4;
    int v[4]; int s = 0;
#pragma unroll
    for (int i = 0; i < 4; ++i) { v[i] = (base + i < N) ? cnt[base + i] : 0; s += v[i]; }
    sh[t] = s;
    __syncthreads();
    for (int ofs = 1; ofs < 256; ofs <<= 1) {
        int vv = (t >= ofs) ? sh[t - ofs] : 0;
        __syncthreads();
        sh[t] += vv;
        __syncthreads();
    }
    int o = bbase[b] + sh[t] - s;
#pragma unroll
    for (int i = 0; i < 4; ++i) {
        int idx = base + i;
        if (idx < N) {
            roff[idx] = o; cur[idx] = o;
            o += v[i];
            if (idx == N - 1) roff[N] = o;
        }
    }
}

// scan of graph counts (G <= 1024), single block of 256 threads
__global__ void k_gscan(const int* __restrict__ gcnt, int* __restrict__ goff, int G, int N) {
    __shared__ int sh[256];
    int t = threadIdx.x;
    int base = t * 4;
    int v[4]; int s = 0;
#pragma unroll
    for (int i = 0; i < 4; ++i) { v[i] = (base + i < G) ? gcnt[base + i] : 0; s += v[i]; }
    sh[t] = s;
    __syncthreads();
    for (int ofs = 1; ofs < 256; ofs <<= 1) {
        int vv = (t >= ofs) ? sh[t - ofs] : 0;
        __syncthreads();
        sh[t] += vv;
        __syncthreads();
    }
    int o = sh[t] - s;
#pragma unroll
    for (int i = 0; i < 4; ++i) {
        int idx = base + i;
        if (idx < G) { goff[idx] = o; o += v[i]; }
    }
    if (t == 255) goff[G] = N;
}

// CSR fill with precomputed edge weights: wcsr[p] = dinv[src]
__global__ void k_fill(const int* __restrict__ src, const int* __restrict__ dst,
                       const float* __restrict__ dinv,
                       int* __restrict__ cur, int* __restrict__ csr,
                       float* __restrict__ wcsr, int E) {
    int i = blockIdx.x * blockDim.x + threadIdx.x;
    if (i < E) {
        int s = src[i];
        int p = atomicAdd(&cur[dst[i]], 1);
        csr[p] = s;
        wcsr[p] = dinv[s];
    }
}

__global__ void k_init_ac(float* __restrict__ a, float* __restrict__ c) {
    int t = threadIdx.x;
    a[t] = 1.0f; c[t] = 0.0f;
}

// Wf[k][j] = a[k]*W[k][j], same for rW
__global__ void k_fold_scale(const float* __restrict__ W, const float* __restrict__ rW,
                             const float* __restrict__ a,
                             float* __restrict__ Wf, float* __restrict__ rWf) {
    int idx = blockIdx.x * 256 + threadIdx.x;  // grid 128 -> 32768 threads
    if (idx < D * D) {
        int k = idx >> 7;
        Wf[idx] = a[k] * W[idx];
    } else {
        int li = idx - D * D;
        int k = li >> 7;
        rWf[li] = a[k] * rW[li];
    }
}

// cwA[j] = sum_k c[k]*W[k][j];  crb[j] = rb[j] + sum_k c[k]*rW[k][j]
__global__ void k_fold_vec(const float* __restrict__ W, const float* __restrict__ rW,
                           const float* __restrict__ c, const float* __restrict__ rb,
                           float* __restrict__ cwA, float* __restrict__ crb) {
    int t = threadIdx.x;  // 256
    if (t < D) {
        float s = 0.f;
        for (int k = 0; k < D; ++k) s += c[k] * W[k * D + t];
        cwA[t] = s;
    } else {
        int j = t - D;
        float s = rb[j];
        for (int k = 0; k < D; ++k) s += c[k] * rW[k * D + j];
        crb[j] = s;
    }
}

// ---------------- fused dual GEMM ----------------
// O0 = F @ W0 + add0 ;  O1 = relu(F @ W1 + add1)
__global__ __launch_bounds__(256) void k_gemm_dual(
    const float* __restrict__ F,
    const float* __restrict__ W0, const float* __restrict__ W1,
    const float* __restrict__ add0, const float* __restrict__ add1,
    float* __restrict__ O0, float* __restrict__ O1, int N) {
    __shared__ float fs[128 * 128];
    const int t = threadIdx.x;
    const int rowbase = blockIdx.x * 128;

    // stage 128x128 f tile, XOR-swizzled on 16B units: su = unit ^ ((row>>3)&7)
#pragma unroll
    for (int i = 0; i < 16; ++i) {
        int l = t + i * 256;          // float4 index 0..4095
        int row = l >> 5;
        int unit = l & 31;
        float4 v = make_float4(0.f, 0.f, 0.f, 0.f);
        int gr = rowbase + row;
        if (gr < N) v = *(const float4*)(F + (size_t)gr * D + unit * 4);
        int su = unit ^ ((row >> 3) & 7);
        *(float4*)&fs[row * 128 + su * 4] = v;
    }
    __syncthreads();

    const int tx = t & 15, ty = t >> 4;
    const int c0 = tx * 8;
    const int r0 = ty * 8;

#pragma unroll 1
    for (int m = 0; m < 2; ++m) {
        const float* __restrict__ W = m ? W1 : W0;
        const float* __restrict__ addv = m ? add1 : add0;
        float* __restrict__ O = m ? O1 : O0;

        float acc[8][8];
#pragma unroll
        for (int i = 0; i < 8; ++i)
#pragma unroll
            for (int j = 0; j < 8; ++j) acc[i][j] = 0.f;

        for (int kc = 0; kc < 128; kc += 4) {
            float fr[8][4];
#pragma unroll
            for (int i = 0; i < 8; ++i) {
                int rr = r0 + i;
                int su = (kc >> 2) ^ ((rr >> 3) & 7);
                float4 t4 = *(const float4*)&fs[rr * 128 + su * 4];
                fr[i][0] = t4.x; fr[i][1] = t4.y; fr[i][2] = t4.z; fr[i][3] = t4.w;
            }
#pragma unroll
            for (int kk = 0; kk < 4; ++kk) {
                float4 wa = *(const float4*)(W + (size_t)(kc + kk) * D + c0);
                float4 wb = *(const float4*)(W + (size_t)(kc + kk) * D + c0 + 4);
                float wv[8] = {wa.x, wa.y, wa.z, wa.w, wb.x, wb.y, wb.z, wb.w};
#pragma unroll
                for (int i = 0; i < 8; ++i) {
                    float fv = fr[i][kk];
#pragma unroll
                    for (int j = 0; j < 8; ++j) acc[i][j] += fv * wv[j];
                }
            }
        }

        float va[8];
#pragma unroll
        for (int j = 0; j < 8; ++j) va[j] = addv[c0 + j];

#pragma unroll
        for (int i = 0; i < 8; ++i) {
            int gr = rowbase + r0 + i;
            if (gr < N) {
                float o0 = acc[i][0] + va[0], o1 = acc[i][1] + va[1];
                float o2 = acc[i][2] + va[2], o3 = acc[i][3] + va[3];
                float o4 = acc[i][4] + va[4], o5 = acc[i][5] + va[5];
                float o6 = acc[i][6] + va[6], o7 = acc[i][7] + va[7];
                if (m == 1) {
                    o0 = fmaxf(o0, 0.f); o1 = fmaxf(o1, 0.f); o2 = fmaxf(o2, 0.f); o3 = fmaxf(o3, 0.f);
                    o4 = fmaxf(o4, 0.f); o5 = fmaxf(o5, 0.f); o6 = fmaxf(o6, 0.f); o7 = fmaxf(o7, 0.f);
                }
                float4 lo = make_float4(o0, o1, o2, o3);
                float4 hi = make_float4(o4, o5, o6, o7);
                *(float4*)(O + (size_t)gr * D + c0) = lo;
                *(float4*)(O + (size_t)gr * D + c0 + 4) = hi;
            }
        }
    }
}

// ---------------- aggregation + residual + BN stats ----------------
// 1 node per wave (64 lanes x float2 -> one 512B row per load).
// Edge loop: scalar head to 4-align e, then int4/float4 uniform loads of
// 4 indices + 4 precomputed weights -> 4 independent float2 row-gathers.
// resf is read for own row then overwritten with the layer output (in-place).
__global__ __launch_bounds__(256) void k_agg(
    const float* __restrict__ h, float* __restrict__ resf,
    const int* __restrict__ roff, const int* __restrict__ csr,
    const float* __restrict__ wcsr,
    const float* __restrict__ dinv, const float* __restrict__ bias,
    float* __restrict__ stats, int N) {
    const int tid = threadIdx.x;
    const int lane = tid & 63;
    const int c = lane * 2;
    const int wid = (blockIdx.x * blockDim.x + tid) >> 6;
    const int nw = (gridDim.x * blockDim.x) >> 6;
    const float b0 = bias[c], b1 = bias[c + 1];
    float sx = 0.f, sy = 0.f, qx = 0.f, qy = 0.f;

    for (int v = wid; v < N; v += nw) {
        int e = roff[v], end = roff[v + 1];
        float ax = 0.f, ay = 0.f;
        // scalar head until e is 4-aligned
        for (; e < end && (e & 3); ++e) {
            int u = csr[e];
            float w = wcsr[e];
            const float2 hv = *(const float2*)(h + (size_t)u * D + c);
            ax += w * hv.x; ay += w * hv.y;
        }
        // 4-wide aligned main loop
        for (; e + 4 <= end; e += 4) {
            const int4   u4 = *(const int4*)(csr + e);
            const float4 w4 = *(const float4*)(wcsr + e);
            const float2 h0 = *(const float2*)(h + (size_t)u4.x * D + c);
            const float2 h1 = *(const float2*)(h + (size_t)u4.y * D + c);
            const float2 h2 = *(const float2*)(h + (size_t)u4.z * D + c);
            const float2 h3 = *(const float2*)(h + (size_t)u4.w * D + c);
            ax += w4.x * h0.x + w4.y * h1.x + w4.z * h2.x + w4.w * h3.x;
            ay += w4.x * h0.y + w4.y * h1.y + w4.z * h2.y + w4.w * h3.y;
        }
        // tail
        for (; e < end; ++e) {
            int u = csr[e];
            float w = wcsr[e];
            const float2 hv = *(const float2*)(h + (size_t)u * D + c);
            ax += w * hv.x; ay += w * hv.y;
        }
        float dv = dinv[v];
        const float2 hs = *(const float2*)(h + (size_t)v * D + c);
        ax = (ax + hs.x * dv) * dv + b0;
        ay = (ay + hs.y * dv) * dv + b1;
        const float2 r = *(const float2*)(resf + (size_t)v * D + c);
        float ox = ax + r.x, oy = ay + r.y;
        *(float2*)(resf + (size_t)v * D + c) = make_float2(ox, oy);
        sx += ox; sy += oy; qx += ox * ox; qy += oy * oy;
    }

    __shared__ float4 red[256];
    red[tid] = make_float4(sx, sy, qx, qy);
    __syncthreads();
    if (tid < 64) {
        float4 a = red[tid];
        float4 b = red[tid + 64];
        float4 cc = red[tid + 128];
        float4 d = red[tid + 192];
        float tsx = a.x + b.x + cc.x + d.x;
        float tsy = a.y + b.y + cc.y + d.y;
        float tqx = a.z + b.z + cc.z + d.z;
        float tqy = a.w + b.w + cc.w + d.w;
        atomicAdd(&stats[c], tsx);
        atomicAdd(&stats[c + 1], tsy);
        atomicAdd(&stats[D + c], tqx);
        atomicAdd(&stats[D + c + 1], tqy);
    }
}

__global__ void k_bnfin(const float* __restrict__ stats, const float* __restrict__ gamma,
                        const float* __restrict__ beta,
                        float* __restrict__ a_next, float* __restrict__ c_next, float invN) {
    int t = threadIdx.x;  // 128
    float mean = stats[t] * invN;
    float var = stats[D + t] * invN - mean * mean;
    float rs = rsqrtf(var + BN_EPS);
    float a = gamma[t] * rs;
    a_next[t] = a;
    c_next[t] = beta[t] - mean * a;
}

// out[g] = (sum_{v in g} f[v]) * a + cnt_g * c
__global__ void k_pool(const float* __restrict__ f, const int* __restrict__ goff,
                       const float* __restrict__ a, const float* __restrict__ c,
                       float* __restrict__ out) {
    int g = blockIdx.x, t = threadIdx.x;  // 128 threads
    int beg = goff[g], end = goff[g + 1];
    float acc = 0.f;
    for (int v = beg; v < end; ++v) acc += f[(size_t)v * D + t];
    out[(size_t)g * D + t] = acc * a[t] + (float)(end - beg) * c[t];
}

// ---------------- launcher ----------------

extern "C" void kernel_launch(void* const* d_in, const int* in_sizes, int n_in,
                              void* d_out, int out_size, void* d_ws, size_t ws_size,
                              hipStream_t stream) {
    const float* x      = (const float*)d_in[0];
    const int*   ei     = (const int*)d_in[1];
    const int*   batch  = (const int*)d_in[2];
    const float* Ws     = (const float*)d_in[3];
    const float* bs     = (const float*)d_in[4];
    const float* rWs    = (const float*)d_in[5];
    const float* rbs    = (const float*)d_in[6];
    const float* gammas = (const float*)d_in[7];
    const float* betas  = (const float*)d_in[8];
    float* out = (float*)d_out;

    const int N = in_sizes[2];
    const int E = in_sizes[1] / 2;
    const int G = out_size / D;
    const int* src = ei;
    const int* dst = ei + E;

    char* ws = (char*)d_ws;
    size_t off = 0;
    auto alloc = [&](size_t bytes) -> char* {
        char* p = ws + off;
        off += (bytes + 255) & ~(size_t)255;
        return p;
    };
    float* h    = (float*)alloc((size_t)N * D * 4);
    float* R0   = (float*)alloc((size_t)N * D * 4);
    float* R1   = (float*)alloc((size_t)N * D * 4);
    int*   csr  = (int*)alloc((size_t)E * 4);
    float* wcsr = (float*)alloc((size_t)E * 4);
    int*   roff = (int*)alloc((size_t)(N + 1) * 4);
    int*   cur  = (int*)alloc((size_t)N * 4);
    int*   cnt  = (int*)alloc((size_t)N * 4);
    float* dinv = (float*)alloc((size_t)N * 4);
    int*   gcnt = (int*)alloc((size_t)G * 4);
    int*   goff = (int*)alloc((size_t)(G + 1) * 4);
    int*   bsum = (int*)alloc(256 * 4);
    int*   bbase= (int*)alloc(256 * 4);
    float* stats= (float*)alloc((size_t)NLAYERS * 2 * D * 4);
    float* aarr = (float*)alloc((size_t)(NLAYERS + 1) * D * 4);
    float* carr = (float*)alloc((size_t)(NLAYERS + 1) * D * 4);
    float* Wf   = (float*)alloc((size_t)D * D * 4);
    float* rWf  = (float*)alloc((size_t)D * D * 4);
    float* cwA  = (float*)alloc(D * 4);
    float* crb  = (float*)alloc(D * 4);
    (void)ws_size;

    hipMemsetAsync(cnt, 0, (size_t)N * 4, stream);
    hipMemsetAsync(gcnt, 0, (size_t)G * 4, stream);
    hipMemsetAsync(stats, 0, (size_t)NLAYERS * 2 * D * 4, stream);

    k_hist_edges<<<(E + 255) / 256, 256, 0, stream>>>(dst, cnt, E);
    k_hist_batch<<<(N + 255) / 256, 256, 0, stream>>>(batch, gcnt, N);
    k_dinv<<<(N + 255) / 256, 256, 0, stream>>>(cnt, dinv, N);

    int nb = (N + 1023) / 1024;
    k_scan_partial<<<nb, 256, 0, stream>>>(cnt, bsum, N);
    k_scan_small<<<1, 256, 0, stream>>>(bsum, bbase, nb);
    k_scan_apply<<<nb, 256, 0, stream>>>(cnt, bbase, roff, cur, N);
    k_gscan<<<1, 256, 0, stream>>>(gcnt, goff, G, N);
    k_fill<<<(E + 255) / 256, 256, 0, stream>>>(src, dst, dinv, cur, csr, wcsr, E);
    k_init_ac<<<1, D, 0, stream>>>(aarr, carr);

    const float* fin = x;
    float* fouts[NLAYERS] = {R0, R1, R0};
    for (int l = 0; l < NLAYERS; ++l) {
        const float* W  = Ws + (size_t)l * D * D;
        const float* rW = rWs + (size_t)l * D * D;
        const float* aP = aarr + (size_t)l * D;
        const float* cP = carr + (size_t)l * D;

        k_fold_scale<<<128, 256, 0, stream>>>(W, rW, aP, Wf, rWf);
        k_fold_vec<<<1, 256, 0, stream>>>(W, rW, cP, rbs + (size_t)l * D, cwA, crb);

        float* fo = fouts[l];
        k_gemm_dual<<<(N + 127) / 128, 256, 0, stream>>>(fin, Wf, rWf, cwA, crb, h, fo, N);
        k_agg<<<4096, 256, 0, stream>>>(h, fo, roff, csr, wcsr, dinv, bs + (size_t)l * D,
                                        stats + (size_t)l * 2 * D, N);
        k_bnfin<<<1, D, 0, stream>>>(stats + (size_t)l * 2 * D, gammas + (size_t)l * D,
                                     betas + (size_t)l * D,
                                     aarr + (size_t)(l + 1) * D, carr + (size_t)(l + 1) * D,
                                     1.0f / (float)N);
        fin = fo;
    }

    k_pool<<<G, D, 0, stream>>>(fin, goff, aarr + (size_t)NLAYERS * D,
                                carr + (size_t)NLAYERS * D, out);
}

// Round 4
// 1442.356 us; speedup vs baseline: 1.0740x; 1.0237x over previous
//
#include <hip/hip_runtime.h>

#define D 128
#define NLAYERS 3
#define BN_EPS 1e-5f

// ---------------- setup kernels ----------------

__global__ void k_hist_edges(const int* __restrict__ dst, int* __restrict__ cnt, int E) {
    int i = blockIdx.x * blockDim.x + threadIdx.x;
    if (i < E) atomicAdd(&cnt[dst[i]], 1);
}

__global__ void k_hist_batch(const int* __restrict__ batch, int* __restrict__ gcnt, int N) {
    int i = blockIdx.x * blockDim.x + threadIdx.x;
    if (i < N) atomicAdd(&gcnt[batch[i]], 1);
}

__global__ void k_dinv(const int* __restrict__ cnt, float* __restrict__ dinv, int N) {
    int i = blockIdx.x * blockDim.x + threadIdx.x;
    if (i < N) dinv[i] = rsqrtf((float)(cnt[i] + 1));   // +1 self loop
}

// partial sums of blocks of 1024 counts
__global__ void k_scan_partial(const int* __restrict__ cnt, int* __restrict__ bsum, int N) {
    __shared__ int sh[256];
    int b = blockIdx.x, t = threadIdx.x;
    int base = b * 1024 + t * 4;
    int s = 0;
#pragma unroll
    for (int i = 0; i < 4; ++i) { int idx = base + i; s += (idx < N) ? cnt[idx] : 0; }
    sh[t] = s;
    for (int ofs = 128; ofs > 0; ofs >>= 1) {
        __syncthreads();
        if (t < ofs) sh[t] += sh[t + ofs];
    }
    __syncthreads();
    if (t == 0) bsum[b] = sh[0];
}

// exclusive scan of up to 256 block sums (single block, 256 threads)
__global__ void k_scan_small(const int* __restrict__ bsum, int* __restrict__ bbase, int nb) {
    __shared__ int sh[256];
    int t = threadIdx.x;
    int v = (t < nb) ? bsum[t] : 0;
    sh[t] = v;
    __syncthreads();
    for (int ofs = 1; ofs < 256; ofs <<= 1) {
        int vv = (t >= ofs) ? sh[t - ofs] : 0;
        __syncthreads();
        sh[t] += vv;
        __syncthreads();
    }
    bbase[t] = sh[t] - v;   // exclusive
}

__global__ void k_scan_apply(const int* __restrict__ cnt, const int* __restrict__ bbase,
                             int* __restrict__ roff, int* __restrict__ cur, int N) {
    __shared__ int sh[256];
    int b = blockIdx.x, t = threadIdx.x;
    int base = b * 1024 + t * 4;
    int v[4]; int s = 0;
#pragma unroll
    for (int i = 0; i < 4; ++i) { v[i] = (base + i < N) ? cnt[base + i] : 0; s += v[i]; }
    sh[t] = s;
    __syncthreads();
    for (int ofs = 1; ofs < 256; ofs <<= 1) {
        int vv = (t >= ofs) ? sh[t - ofs] : 0;
        __syncthreads();
        sh[t] += vv;
        __syncthreads();
    }
    int o = bbase[b] + sh[t] - s;
#pragma unroll
    for (int i = 0; i < 4; ++i) {
        int idx = base + i;
        if (idx < N) {
            roff[idx] = o; cur[idx] = o;
            o += v[i];
            if (idx == N - 1) roff[N] = o;
        }
    }
}

// scan of graph counts (G <= 1024), single block of 256 threads
__global__ void k_gscan(const int* __restrict__ gcnt, int* __restrict__ goff, int G, int N) {
    __shared__ int sh[256];
    int t = threadIdx.x;
    int base = t * 4;
    int v[4]; int s = 0;
#pragma unroll
    for (int i = 0; i < 4; ++i) { v[i] = (base + i < G) ? gcnt[base + i] : 0; s += v[i]; }
    sh[t] = s;
    __syncthreads();
    for (int ofs = 1; ofs < 256; ofs <<= 1) {
        int vv = (t >= ofs) ? sh[t - ofs] : 0;
        __syncthreads();
        sh[t] += vv;
        __syncthreads();
    }
    int o = sh[t] - s;
#pragma unroll
    for (int i = 0; i < 4; ++i) {
        int idx = base + i;
        if (idx < G) { goff[idx] = o; o += v[i]; }
    }
    if (t == 255) goff[G] = N;
}

// CSR fill with precomputed edge weights: wcsr[p] = dinv[src]
__global__ void k_fill(const int* __restrict__ src, const int* __restrict__ dst,
                       const float* __restrict__ dinv,
                       int* __restrict__ cur, int* __restrict__ csr,
                       float* __restrict__ wcsr, int E) {
    int i = blockIdx.x * blockDim.x + threadIdx.x;
    if (i < E) {
        int s = src[i];
        int p = atomicAdd(&cur[dst[i]], 1);
        csr[p] = s;
        wcsr[p] = dinv[s];
    }
}

__global__ void k_init_ac(float* __restrict__ a, float* __restrict__ c) {
    int t = threadIdx.x;
    a[t] = 1.0f; c[t] = 0.0f;
}

// Wf[k][j] = a[k]*W[k][j], same for rW
__global__ void k_fold_scale(const float* __restrict__ W, const float* __restrict__ rW,
                             const float* __restrict__ a,
                             float* __restrict__ Wf, float* __restrict__ rWf) {
    int idx = blockIdx.x * 256 + threadIdx.x;  // grid 128 -> 32768 threads
    if (idx < D * D) {
        int k = idx >> 7;
        Wf[idx] = a[k] * W[idx];
    } else {
        int li = idx - D * D;
        int k = li >> 7;
        rWf[li] = a[k] * rW[li];
    }
}

// cwA[j] = sum_k c[k]*W[k][j];  crb[j] = rb[j] + sum_k c[k]*rW[k][j]
__global__ void k_fold_vec(const float* __restrict__ W, const float* __restrict__ rW,
                           const float* __restrict__ c, const float* __restrict__ rb,
                           float* __restrict__ cwA, float* __restrict__ crb) {
    int t = threadIdx.x;  // 256
    if (t < D) {
        float s = 0.f;
        for (int k = 0; k < D; ++k) s += c[k] * W[k * D + t];
        cwA[t] = s;
    } else {
        int j = t - D;
        float s = rb[j];
        for (int k = 0; k < D; ++k) s += c[k] * rW[k * D + j];
        crb[j] = s;
    }
}

// ---------------- fused dual GEMM ----------------
// O0 = F @ W0 + add0 ;  O1 = relu(F @ W1 + add1)
__global__ __launch_bounds__(256) void k_gemm_dual(
    const float* __restrict__ F,
    const float* __restrict__ W0, const float* __restrict__ W1,
    const float* __restrict__ add0, const float* __restrict__ add1,
    float* __restrict__ O0, float* __restrict__ O1, int N) {
    __shared__ float fs[128 * 128];
    const int t = threadIdx.x;
    const int rowbase = blockIdx.x * 128;

    // stage 128x128 f tile, XOR-swizzled on 16B units: su = unit ^ ((row>>3)&7)
#pragma unroll
    for (int i = 0; i < 16; ++i) {
        int l = t + i * 256;          // float4 index 0..4095
        int row = l >> 5;
        int unit = l & 31;
        float4 v = make_float4(0.f, 0.f, 0.f, 0.f);
        int gr = rowbase + row;
        if (gr < N) v = *(const float4*)(F + (size_t)gr * D + unit * 4);
        int su = unit ^ ((row >> 3) & 7);
        *(float4*)&fs[row * 128 + su * 4] = v;
    }
    __syncthreads();

    const int tx = t & 15, ty = t >> 4;
    const int c0 = tx * 8;
    const int r0 = ty * 8;

#pragma unroll 1
    for (int m = 0; m < 2; ++m) {
        const float* __restrict__ W = m ? W1 : W0;
        const float* __restrict__ addv = m ? add1 : add0;
        float* __restrict__ O = m ? O1 : O0;

        float acc[8][8];
#pragma unroll
        for (int i = 0; i < 8; ++i)
#pragma unroll
            for (int j = 0; j < 8; ++j) acc[i][j] = 0.f;

        for (int kc = 0; kc < 128; kc += 4) {
            float fr[8][4];
#pragma unroll
            for (int i = 0; i < 8; ++i) {
                int rr = r0 + i;
                int su = (kc >> 2) ^ ((rr >> 3) & 7);
                float4 t4 = *(const float4*)&fs[rr * 128 + su * 4];
                fr[i][0] = t4.x; fr[i][1] = t4.y; fr[i][2] = t4.z; fr[i][3] = t4.w;
            }
#pragma unroll
            for (int kk = 0; kk < 4; ++kk) {
                float4 wa = *(const float4*)(W + (size_t)(kc + kk) * D + c0);
                float4 wb = *(const float4*)(W + (size_t)(kc + kk) * D + c0 + 4);
                float wv[8] = {wa.x, wa.y, wa.z, wa.w, wb.x, wb.y, wb.z, wb.w};
#pragma unroll
                for (int i = 0; i < 8; ++i) {
                    float fv = fr[i][kk];
#pragma unroll
                    for (int j = 0; j < 8; ++j) acc[i][j] += fv * wv[j];
                }
            }
        }

        float va[8];
#pragma unroll
        for (int j = 0; j < 8; ++j) va[j] = addv[c0 + j];

#pragma unroll
        for (int i = 0; i < 8; ++i) {
            int gr = rowbase + r0 + i;
            if (gr < N) {
                float o0 = acc[i][0] + va[0], o1 = acc[i][1] + va[1];
                float o2 = acc[i][2] + va[2], o3 = acc[i][3] + va[3];
                float o4 = acc[i][4] + va[4], o5 = acc[i][5] + va[5];
                float o6 = acc[i][6] + va[6], o7 = acc[i][7] + va[7];
                if (m == 1) {
                    o0 = fmaxf(o0, 0.f); o1 = fmaxf(o1, 0.f); o2 = fmaxf(o2, 0.f); o3 = fmaxf(o3, 0.f);
                    o4 = fmaxf(o4, 0.f); o5 = fmaxf(o5, 0.f); o6 = fmaxf(o6, 0.f); o7 = fmaxf(o7, 0.f);
                }
                float4 lo = make_float4(o0, o1, o2, o3);
                float4 hi = make_float4(o4, o5, o6, o7);
                *(float4*)(O + (size_t)gr * D + c0) = lo;
                *(float4*)(O + (size_t)gr * D + c0 + 4) = hi;
            }
        }
    }
}

// ---------------- aggregation + residual + BN stats ----------------
// 1 node per wave (64 lanes x float2 = one 512B row per gather).
// Edge loop: 2-stage software pipeline over groups of 8 edges — while the
// h-row gathers of group i are in flight, the (wave-uniform) index/weight
// loads of group i+1 are already issued. All unrolled indices are
// compile-time constants -> registers, no scratch.
__global__ __launch_bounds__(256) void k_agg(
    const float* __restrict__ h, float* __restrict__ resf,
    const int* __restrict__ roff, const int* __restrict__ csr,
    const float* __restrict__ wcsr,
    const float* __restrict__ dinv, const float* __restrict__ bias,
    float* __restrict__ stats, int N) {
    const int tid = threadIdx.x;
    const int lane = tid & 63;
    const int c = lane * 2;
    const int wid = (blockIdx.x * blockDim.x + tid) >> 6;
    const int nw = (gridDim.x * blockDim.x) >> 6;
    const float b0 = bias[c], b1 = bias[c + 1];
    float sx = 0.f, sy = 0.f, qx = 0.f, qy = 0.f;

    for (int v = wid; v < N; v += nw) {
        int e = roff[v];
        const int end = roff[v + 1];
        float ax = 0.f, ay = 0.f;

        if (e + 8 <= end) {
            // prologue: load group 0 indices+weights
            int uc[8]; float wc[8];
#pragma unroll
            for (int k = 0; k < 8; ++k) { uc[k] = csr[e + k]; wc[k] = wcsr[e + k]; }
            e += 8;
            // steady state: load next group while gathering current
            while (e + 8 <= end) {
                int un[8]; float wn[8];
#pragma unroll
                for (int k = 0; k < 8; ++k) { un[k] = csr[e + k]; wn[k] = wcsr[e + k]; }
                float2 g[8];
#pragma unroll
                for (int k = 0; k < 8; ++k)
                    g[k] = *(const float2*)(h + (size_t)uc[k] * D + c);
#pragma unroll
                for (int k = 0; k < 8; ++k) { ax += wc[k] * g[k].x; ay += wc[k] * g[k].y; }
#pragma unroll
                for (int k = 0; k < 8; ++k) { uc[k] = un[k]; wc[k] = wn[k]; }
                e += 8;
            }
            // drain last loaded group
            float2 g[8];
#pragma unroll
            for (int k = 0; k < 8; ++k)
                g[k] = *(const float2*)(h + (size_t)uc[k] * D + c);
#pragma unroll
            for (int k = 0; k < 8; ++k) { ax += wc[k] * g[k].x; ay += wc[k] * g[k].y; }
        }
        // tail (< 8 edges)
        for (; e < end; ++e) {
            int u = csr[e];
            float w = wcsr[e];
            const float2 hv = *(const float2*)(h + (size_t)u * D + c);
            ax += w * hv.x; ay += w * hv.y;
        }

        float dv = dinv[v];
        const float2 hs = *(const float2*)(h + (size_t)v * D + c);
        ax = (ax + hs.x * dv) * dv + b0;
        ay = (ay + hs.y * dv) * dv + b1;
        const float2 r = *(const float2*)(resf + (size_t)v * D + c);
        float ox = ax + r.x, oy = ay + r.y;
        *(float2*)(resf + (size_t)v * D + c) = make_float2(ox, oy);
        sx += ox; sy += oy; qx += ox * ox; qy += oy * oy;
    }

    __shared__ float4 red[256];
    red[tid] = make_float4(sx, sy, qx, qy);
    __syncthreads();
    if (tid < 64) {
        float4 a = red[tid];
        float4 b = red[tid + 64];
        float4 cc = red[tid + 128];
        float4 d = red[tid + 192];
        float tsx = a.x + b.x + cc.x + d.x;
        float tsy = a.y + b.y + cc.y + d.y;
        float tqx = a.z + b.z + cc.z + d.z;
        float tqy = a.w + b.w + cc.w + d.w;
        atomicAdd(&stats[c], tsx);
        atomicAdd(&stats[c + 1], tsy);
        atomicAdd(&stats[D + c], tqx);
        atomicAdd(&stats[D + c + 1], tqy);
    }
}

__global__ void k_bnfin(const float* __restrict__ stats, const float* __restrict__ gamma,
                        const float* __restrict__ beta,
                        float* __restrict__ a_next, float* __restrict__ c_next, float invN) {
    int t = threadIdx.x;  // 128
    float mean = stats[t] * invN;
    float var = stats[D + t] * invN - mean * mean;
    float rs = rsqrtf(var + BN_EPS);
    float a = gamma[t] * rs;
    a_next[t] = a;
    c_next[t] = beta[t] - mean * a;
}

// out[g] = (sum_{v in g} f[v]) * a + cnt_g * c
__global__ void k_pool(const float* __restrict__ f, const int* __restrict__ goff,
                       const float* __restrict__ a, const float* __restrict__ c,
                       float* __restrict__ out) {
    int g = blockIdx.x, t = threadIdx.x;  // 128 threads
    int beg = goff[g], end = goff[g + 1];
    float acc = 0.f;
    for (int v = beg; v < end; ++v) acc += f[(size_t)v * D + t];
    out[(size_t)g * D + t] = acc * a[t] + (float)(end - beg) * c[t];
}

// ---------------- launcher ----------------

extern "C" void kernel_launch(void* const* d_in, const int* in_sizes, int n_in,
                              void* d_out, int out_size, void* d_ws, size_t ws_size,
                              hipStream_t stream) {
    const float* x      = (const float*)d_in[0];
    const int*   ei     = (const int*)d_in[1];
    const int*   batch  = (const int*)d_in[2];
    const float* Ws     = (const float*)d_in[3];
    const float* bs     = (const float*)d_in[4];
    const float* rWs    = (const float*)d_in[5];
    const float* rbs    = (const float*)d_in[6];
    const float* gammas = (const float*)d_in[7];
    const float* betas  = (const float*)d_in[8];
    float* out = (float*)d_out;

    const int N = in_sizes[2];
    const int E = in_sizes[1] / 2;
    const int G = out_size / D;
    const int* src = ei;
    const int* dst = ei + E;

    char* ws = (char*)d_ws;
    size_t off = 0;
    auto alloc = [&](size_t bytes) -> char* {
        char* p = ws + off;
        off += (bytes + 255) & ~(size_t)255;
        return p;
    };
    float* h    = (float*)alloc((size_t)N * D * 4);
    float* R0   = (float*)alloc((size_t)N * D * 4);
    float* R1   = (float*)alloc((size_t)N * D * 4);
    int*   csr  = (int*)alloc((size_t)E * 4);
    float* wcsr = (float*)alloc((size_t)E * 4);
    int*   roff = (int*)alloc((size_t)(N + 1) * 4);
    int*   cur  = (int*)alloc((size_t)N * 4);
    int*   cnt  = (int*)alloc((size_t)N * 4);
    float* dinv = (float*)alloc((size_t)N * 4);
    int*   gcnt = (int*)alloc((size_t)G * 4);
    int*   goff = (int*)alloc((size_t)(G + 1) * 4);
    int*   bsum = (int*)alloc(256 * 4);
    int*   bbase= (int*)alloc(256 * 4);
    float* stats= (float*)alloc((size_t)NLAYERS * 2 * D * 4);
    float* aarr = (float*)alloc((size_t)(NLAYERS + 1) * D * 4);
    float* carr = (float*)alloc((size_t)(NLAYERS + 1) * D * 4);
    float* Wf   = (float*)alloc((size_t)D * D * 4);
    float* rWf  = (float*)alloc((size_t)D * D * 4);
    float* cwA  = (float*)alloc(D * 4);
    float* crb  = (float*)alloc(D * 4);
    (void)ws_size;

    hipMemsetAsync(cnt, 0, (size_t)N * 4, stream);
    hipMemsetAsync(gcnt, 0, (size_t)G * 4, stream);
    hipMemsetAsync(stats, 0, (size_t)NLAYERS * 2 * D * 4, stream);

    k_hist_edges<<<(E + 255) / 256, 256, 0, stream>>>(dst, cnt, E);
    k_hist_batch<<<(N + 255) / 256, 256, 0, stream>>>(batch, gcnt, N);
    k_dinv<<<(N + 255) / 256, 256, 0, stream>>>(cnt, dinv, N);

    int nb = (N + 1023) / 1024;
    k_scan_partial<<<nb, 256, 0, stream>>>(cnt, bsum, N);
    k_scan_small<<<1, 256, 0, stream>>>(bsum, bbase, nb);
    k_scan_apply<<<nb, 256, 0, stream>>>(cnt, bbase, roff, cur, N);
    k_gscan<<<1, 256, 0, stream>>>(gcnt, goff, G, N);
    k_fill<<<(E + 255) / 256, 256, 0, stream>>>(src, dst, dinv, cur, csr, wcsr, E);
    k_init_ac<<<1, D, 0, stream>>>(aarr, carr);

    const float* fin = x;
    float* fouts[NLAYERS] = {R0, R1, R0};
    for (int l = 0; l < NLAYERS; ++l) {
        const float* W  = Ws + (size_t)l * D * D;
        const float* rW = rWs + (size_t)l * D * D;
        const float* aP = aarr + (size_t)l * D;
        const float* cP = carr + (size_t)l * D;

        k_fold_scale<<<128, 256, 0, stream>>>(W, rW, aP, Wf, rWf);
        k_fold_vec<<<1, 256, 0, stream>>>(W, rW, cP, rbs + (size_t)l * D, cwA, crb);

        float* fo = fouts[l];
        k_gemm_dual<<<(N + 127) / 128, 256, 0, stream>>>(fin, Wf, rWf, cwA, crb, h, fo, N);
        k_agg<<<4096, 256, 0, stream>>>(h, fo, roff, csr, wcsr, dinv, bs + (size_t)l * D,
                                        stats + (size_t)l * 2 * D, N);
        k_bnfin<<<1, D, 0, stream>>>(stats + (size_t)l * 2 * D, gammas + (size_t)l * D,
                                     betas + (size_t)l * D,
                                     aarr + (size_t)(l + 1) * D, carr + (size_t)(l + 1) * D,
                                     1.0f / (float)N);
        fin = fo;
    }

    k_pool<<<G, D, 0, stream>>>(fin, goff, aarr + (size_t)NLAYERS * D,
                                carr + (size_t)NLAYERS * D, out);
}